// Round 13
// baseline (649.412 us; speedup 1.0000x reference)
//
#include <hip/hip_runtime.h>

typedef _Float16 v8hf __attribute__((ext_vector_type(8)));
typedef float    v4f  __attribute__((ext_vector_type(4)));

#define MFMA16(a, b, c) __builtin_amdgcn_mfma_f32_16x16x32_f16((a), (b), (c), 0, 0, 0)

#define TT 512
#define BT 16       // batch rows (= MFMA B/C cols)
#define NTH 704     // 11 waves: w0-3 L1(quarter), w4-7 L2(quarter), w8-9 L3+head(half), w10 flush
#define KS 2.8853900817779268f   // 2*log2(e), folded into weights+biases
#define CL 13.8498724f           // 4.8 * KS

// Dynamic LDS (bytes). nu(r,g,e) = 32r + 16(e>>2) + 4g + (e&3) (A and B share it).
//   h1 ring: 8 entries x 4096 @ 0      (entry = step&7; 4 slots x 64 lanes x 16 B)
//   h2 ring: 8 entries x 2048 @ 32768
//   xst:     513 x 64         @ 49152  (u32 f16-pair per (t,b))
//   oring:   [b][64][2] f32   @ 81984  (512 B per b)
#define H1R 0u
#define H2R 32768u
#define XST 49152u
#define ORG 81984u
#define SMEMB 90176

extern __shared__ __align__(16) char SMp[];

// tanh of pre-scaled z (z = KS*preact): 4 exp2 + 1 rcp; clamp |x|<=4.8 (err 1.35e-4).
__device__ __forceinline__ v4f tanh4s(v4f z) {
    float z0 = __builtin_amdgcn_fmed3f(z[0], -CL, CL);
    float z1 = __builtin_amdgcn_fmed3f(z[1], -CL, CL);
    float z2 = __builtin_amdgcn_fmed3f(z[2], -CL, CL);
    float z3 = __builtin_amdgcn_fmed3f(z[3], -CL, CL);
    float a0 = __builtin_amdgcn_exp2f(z0) + 1.f;
    float a1 = __builtin_amdgcn_exp2f(z1) + 1.f;
    float a2 = __builtin_amdgcn_exp2f(z2) + 1.f;
    float a3 = __builtin_amdgcn_exp2f(z3) + 1.f;
    float P = a0 * a1, Q = a2 * a3;
    float R = __builtin_amdgcn_rcpf(P * Q);
    float iP = Q * R, iQ = P * R;
    v4f t;
    t[0] = 1.f - 2.f * (a1 * iP);
    t[1] = 1.f - 2.f * (a0 * iP);
    t[2] = 1.f - 2.f * (a3 * iQ);
    t[3] = 1.f - 2.f * (a2 * iQ);
    return t;
}

__device__ __forceinline__ unsigned pk2h(float a, float b) {
    union { _Float16 h[2]; unsigned u; } x;
    x.h[0] = (_Float16)a; x.h[1] = (_Float16)b;
    return x.u;
}
__device__ __forceinline__ v8hf mk8(unsigned a, unsigned b, unsigned c, unsigned d) {
    union { unsigned u[4]; v8hf h; } x;
    x.u[0] = a; x.u[1] = b; x.u[2] = c; x.u[3] = d;
    return x.h;
}

__global__ __launch_bounds__(NTH, 1)
void rnn3_bs(const float* __restrict__ xg,
             const float* __restrict__ Wih1, const float* __restrict__ Whh1,
             const float* __restrict__ bih1, const float* __restrict__ bhh1,
             const float* __restrict__ Wih2, const float* __restrict__ Whh2,
             const float* __restrict__ bih2, const float* __restrict__ bhh2,
             const float* __restrict__ Wih3, const float* __restrict__ Whh3,
             const float* __restrict__ bih3, const float* __restrict__ bhh3,
             const float* __restrict__ Wo1,  const float* __restrict__ bo1,
             const float* __restrict__ Wo2,  const float* __restrict__ bo2,
             float* __restrict__ outg)
{
    const int tid   = threadIdx.x;
    const int lane  = tid & 63;
    const int wid   = tid >> 6;    // SIMD = wid & 3
    const int col   = lane & 15;   // global batch index in B/C frags
    const int g     = lane >> 4;
    const int bbase = blockIdx.x * BT;
    const unsigned l16 = (unsigned)lane * 16u;
    const v4f z4 = {0.f, 0.f, 0.f, 0.f};

    // ---- stage x as f16 pairs [t][b]; zero pad slot 512 ----
    for (int i = tid; i < BT * TT; i += NTH) {
        const int b = i >> 9, t = i & 511;
        float2 xv = *(const float2*)(xg + (size_t)(bbase + b) * (TT * 2) + 2 * t);
        *(unsigned*)(SMp + XST + (unsigned)t * 64u + (unsigned)b * 4u) = pk2h(xv.x, xv.y);
    }
    if (tid < 16) *(unsigned*)(SMp + XST + 512u * 64u + (unsigned)tid * 4u) = 0u;
    __syncthreads();

    auto ldA = [&](const float* W, int rows, int cols, int jg, int kt) -> v8hf {
        v8hf r;
        #pragma unroll
        for (int e = 0; e < 8; ++e) {
            const int kl = 32 * kt + 16 * (e >> 2) + 4 * g + (e & 3);
            float v = (jg < rows && kl < cols) ? W[jg * cols + kl] * KS : 0.f;
            r[e] = (_Float16)v;
        }
        return r;
    };
    auto ldA1 = [&](int jg, int kt) -> v8hf {   // Whh1 + x weights at logical 112,113
        v8hf r;
        #pragma unroll
        for (int e = 0; e < 8; ++e) {
            const int kl = 32 * kt + 16 * (e >> 2) + 4 * g + (e & 3);
            float v = 0.f;
            if (jg < 100) {
                if (kl < 100)       v = Whh1[jg * 100 + kl];
                else if (kl == 112) v = Wih1[jg * 2];
                else if (kl == 113) v = Wih1[jg * 2 + 1];
            }
            r[e] = (_Float16)(v * KS);
        }
        return r;
    };
    auto mkbias = [&](const float* bi, const float* bh, int n, int t) -> v4f {
        v4f b;
        #pragma unroll
        for (int i = 0; i < 4; ++i) {
            const int j = 16 * t + 4 * g + i;
            b[i] = (j < n) ? KS * (bi[j] + bh[j]) : 0.f;
        }
        return b;
    };

    if (wid < 4) {
        // ============ L1, batch-quarter wid: full recurrence in registers ============
        v8hf W1[7][4]; v4f B1[7];
        #pragma unroll
        for (int t = 0; t < 7; ++t) {
            #pragma unroll
            for (int kt = 0; kt < 4; ++kt) W1[t][kt] = ldA1(16 * t + col, kt);
            B1[t] = mkbias(bih1, bhh1, 100, t);
        }
        v8hf S0 = (v8hf)(_Float16)0.f, S1 = S0, S2 = S0, S3;
        {
            unsigned x0 = *(const unsigned*)(SMp + XST + (unsigned)col * 4u);
            S3 = mk8(0u, 0u, (g == 0) ? x0 : 0u, 0u);
        }
        const bool own = ((col >> 2) == wid);
        auto step = [&](int s) {
            if (s >= TT) return;
            unsigned xn = *(const unsigned*)(SMp + XST + (unsigned)(s + 1) * 64u + (unsigned)col * 4u);
            unsigned lo[7], hi[7];
            #pragma unroll
            for (int t = 0; t < 7; ++t) {
                v4f p = B1[t], q = z4;
                p = MFMA16(W1[t][0], S0, p); q = MFMA16(W1[t][1], S1, q);
                p = MFMA16(W1[t][2], S2, p); q = MFMA16(W1[t][3], S3, q);
                v4f r = tanh4s(p + q);
                lo[t] = pk2h(r[0], r[1]); hi[t] = pk2h(r[2], r[3]);
            }
            S0 = mk8(lo[0], hi[0], lo[1], hi[1]);
            S1 = mk8(lo[2], hi[2], lo[3], hi[3]);
            S2 = mk8(lo[4], hi[4], lo[5], hi[5]);
            S3 = mk8(lo[6], hi[6], (g == 0) ? xn : 0u, 0u);
            if (own) {
                char* wb = SMp + H1R + (unsigned)(s & 7) * 4096u + l16;
                *(v8hf*)(wb)         = S0;
                *(v8hf*)(wb + 1024)  = S1;
                *(v8hf*)(wb + 2048)  = S2;
                *(v8hf*)(wb + 3072)  = S3;
            }
        };
        for (int s0 = 0; s0 < 520; s0 += 4) {
            step(s0); step(s0 + 1); step(s0 + 2); step(s0 + 3);
            __syncthreads();
        }
    } else if (wid < 8) {
        // ============ L2, batch-quarter wid-4, lag 4 ============
        const int q2 = wid - 4;
        v8hf Wi2[4][4], Wh2[4][2]; v4f B2[4];
        #pragma unroll
        for (int t = 0; t < 4; ++t) {
            #pragma unroll
            for (int kt = 0; kt < 4; ++kt) Wi2[t][kt] = ldA(Wih2, 60, 100, 16 * t + col, kt);
            Wh2[t][0] = ldA(Whh2, 60, 60, 16 * t + col, 0);
            Wh2[t][1] = ldA(Whh2, 60, 60, 16 * t + col, 1);
            B2[t] = mkbias(bih2, bhh2, 60, t);
        }
        v8hf T0 = (v8hf)(_Float16)0.f, T1 = T0;
        const bool own = ((col >> 2) == q2);
        auto step = [&](int s) {
            if (s < 4 || s >= TT + 4) return;
            const int t = s - 4;
            const char* rb = SMp + H1R + (unsigned)(t & 7) * 4096u + l16;
            v8hf G0 = *(const v8hf*)(rb);
            v8hf G1 = *(const v8hf*)(rb + 1024);
            v8hf G2 = *(const v8hf*)(rb + 2048);
            v8hf G3 = *(const v8hf*)(rb + 3072);
            unsigned lo[4], hi[4];
            #pragma unroll
            for (int tt = 0; tt < 4; ++tt) {
                v4f p = B2[tt], q = z4;
                p = MFMA16(Wi2[tt][0], G0, p); q = MFMA16(Wi2[tt][1], G1, q);
                p = MFMA16(Wi2[tt][2], G2, p); q = MFMA16(Wi2[tt][3], G3, q);
                p = MFMA16(Wh2[tt][0], T0, p); q = MFMA16(Wh2[tt][1], T1, q);
                v4f r = tanh4s(p + q);
                lo[tt] = pk2h(r[0], r[1]); hi[tt] = pk2h(r[2], r[3]);
            }
            T0 = mk8(lo[0], hi[0], lo[1], hi[1]);
            T1 = mk8(lo[2], hi[2], lo[3], hi[3]);
            if (own) {
                char* wb = SMp + H2R + (unsigned)(t & 7) * 2048u + l16;
                *(v8hf*)(wb)        = T0;
                *(v8hf*)(wb + 1024) = T1;
            }
        };
        for (int s0 = 0; s0 < 520; s0 += 4) {
            step(s0); step(s0 + 1); step(s0 + 2); step(s0 + 3);
            __syncthreads();
        }
    } else if (wid < 10) {
        // ============ L3 + head, batch-half wid-8, lag 8 ============
        const int hh = wid - 8;
        v8hf Wi3[2][2], Wh3[2], We; v4f B3[2], BH;
        #pragma unroll
        for (int t = 0; t < 2; ++t) {
            Wi3[t][0] = ldA(Wih3, 30, 60, 16 * t + col, 0);
            Wi3[t][1] = ldA(Wih3, 30, 60, 16 * t + col, 1);
            Wh3[t]    = ldA(Whh3, 30, 30, 16 * t + col, 0);
            B3[t] = mkbias(bih3, bhh3, 30, t);
        }
        #pragma unroll
        for (int e = 0; e < 8; ++e) {   // W_eff = Wo2 @ Wo1 (2 x 30), UNscaled
            const int kl = 16 * (e >> 2) + 4 * g + (e & 3);
            float v = 0.f;
            if (col < 2 && kl < 30) {
                #pragma unroll
                for (int u = 0; u < 10; ++u) v += Wo2[col * 10 + u] * Wo1[u * 30 + kl];
            }
            We[e] = (_Float16)v;
        }
        #pragma unroll
        for (int i = 0; i < 4; ++i) {
            float bv = 0.f;
            if (g == 0 && i < 2) {
                bv = bo2[i];
                #pragma unroll
                for (int u = 0; u < 10; ++u) bv += Wo2[i * 10 + u] * bo1[u];
            }
            BH[i] = bv;
        }
        v8hf S3r = (v8hf)(_Float16)0.f;
        const bool ownO = (g == 0) && ((col >> 3) == hh);
        auto step = [&](int s) {
            if (s < 8 || s >= TT + 8) return;
            const int t = s - 8;
            const char* rb = SMp + H2R + (unsigned)(t & 7) * 2048u + l16;
            v8hf G0 = *(const v8hf*)(rb);
            v8hf G1 = *(const v8hf*)(rb + 1024);
            unsigned lo[2], hi[2];
            #pragma unroll
            for (int tt = 0; tt < 2; ++tt) {
                v4f p = B3[tt], q = z4;
                p = MFMA16(Wi3[tt][0], G0, p); q = MFMA16(Wi3[tt][1], G1, q);
                p = MFMA16(Wh3[tt], S3r, p);
                v4f r = tanh4s(p + q);
                lo[tt] = pk2h(r[0], r[1]); hi[tt] = pk2h(r[2], r[3]);
            }
            S3r = mk8(lo[0], hi[0], lo[1], hi[1]);
            v4f o = BH;
            o = MFMA16(We, S3r, o);
            if (ownO)
                *(float2*)(SMp + ORG + (unsigned)col * 512u + ((unsigned)t & 63u) * 8u) =
                    make_float2(o[0], o[1]);
        };
        for (int s0 = 0; s0 < 520; s0 += 4) {
            step(s0); step(s0 + 1); step(s0 + 2); step(s0 + 3);
            __syncthreads();
        }
    } else {
        // ============ flush wave ============
        auto flushfn = [&](int tbase) {
            const unsigned rb = ORG + (((unsigned)tbase & 63u) >> 1) * 16u;
            #pragma unroll
            for (int jj = 0; jj < 4; ++jj) {
                const int f = lane + 64 * jj;
                const int b = f >> 4, k = f & 15;
                float4 v = *(const float4*)(SMp + rb + (unsigned)b * 512u + (unsigned)k * 16u);
                *(float4*)(outg + ((size_t)(bbase + b) * TT + tbase) * 2 + 4 * k) = v;
            }
        };
        for (int s0 = 0; s0 < 520; s0 += 4) {
            if (s0 >= 48 && ((s0 - 48) & 31) == 0) flushfn(s0 - 48);   // tbase 0..448
            __syncthreads();
        }
        flushfn(480);   // head(480..511) complete and barrier-ordered
    }
}

extern "C" void kernel_launch(void* const* d_in, const int* in_sizes, int n_in,
                              void* d_out, int out_size, void* d_ws, size_t ws_size,
                              hipStream_t stream) {
    (void)in_sizes; (void)n_in; (void)d_ws; (void)ws_size; (void)out_size;
    const float* x     = (const float*)d_in[0];
    const float* W_ih1 = (const float*)d_in[1];
    const float* W_hh1 = (const float*)d_in[2];
    const float* b_ih1 = (const float*)d_in[3];
    const float* b_hh1 = (const float*)d_in[4];
    const float* W_ih2 = (const float*)d_in[5];
    const float* W_hh2 = (const float*)d_in[6];
    const float* b_ih2 = (const float*)d_in[7];
    const float* b_hh2 = (const float*)d_in[8];
    const float* W_ih3 = (const float*)d_in[9];
    const float* W_hh3 = (const float*)d_in[10];
    const float* b_ih3 = (const float*)d_in[11];
    const float* b_hh3 = (const float*)d_in[12];
    const float* W_o1  = (const float*)d_in[13];
    const float* b_o1  = (const float*)d_in[14];
    const float* W_o2  = (const float*)d_in[15];
    const float* b_o2  = (const float*)d_in[16];
    float* out = (float*)d_out;

    hipFuncSetAttribute((const void*)rnn3_bs,
                        hipFuncAttributeMaxDynamicSharedMemorySize, SMEMB);
    rnn3_bs<<<2048 / BT, NTH, SMEMB, stream>>>(
        x, W_ih1, W_hh1, b_ih1, b_hh1,
        W_ih2, W_hh2, b_ih2, b_hh2,
        W_ih3, W_hh3, b_ih3, b_hh3,
        W_o1, b_o1, W_o2, b_o2, out);
}